// Round 14
// baseline (78.911 us; speedup 1.0000x reference)
//
#include <hip/hip_runtime.h>

// PolyAttn collapse: a = s^4/|s^4| == 1.0 identically, so
//   out[b,n,:] = vsum[b,:] @ w_o  (independent of n, q, k, alpha),
//   vsum[b,:]  = (sum_n x[b,n,:]) @ w_qkv[:, 2H:3H].
// R14: CALIBRATION ROUND. Six different pipelines all land 29-31us; no
// per-kernel timings visible (harness fills mask top-5). kOut2 is
// idempotent -> launch it 5x (bit-identical kernels to R13).
//   t_kOut2 = (R14 - R13)/4;  t_kXV = R13 - t_kOut2.
// This decides whether the ~30us lives in the write-side kernel, the
// read-side kernel, or a fixed per-replay overhead.

#define B_ 4
#define N_ 2048
#define D_ 1024
#define H_ 1024
#define H3_ 3072

__device__ __forceinline__ void f4add(float4& a, const float4 b) {
    a.x += b.x; a.y += b.y; a.z += b.z; a.w += b.w;
}

// ws layout (floats): vspart[64][4][1024] (1 MB)

// ---- kXV: 256 blocks (b*64+s): colsum x[b,:,s*16..+16] then @Wv slice ------
__global__ __launch_bounds__(256) void kXV(const float* __restrict__ x,
                                           const float* __restrict__ w_qkv,
                                           float4* __restrict__ vspart4) {
    const int blk = blockIdx.x;
    const int b = blk >> 6, s = blk & 63;
    const int t = threadIdx.x;
    const int c4 = t & 3;                  // float4 col within 16-float slice
    const int rs = t >> 2;                 // 64 row streams
    __shared__ float4 s_acc[256];

    const float4* x4 = reinterpret_cast<const float4*>(x);
    float4 acc = make_float4(0.f, 0.f, 0.f, 0.f);
    size_t base = ((size_t)b * N_ + rs) * (D_ / 4) + s * 4 + c4;
#pragma unroll 16
    for (int i = 0; i < 32; ++i)           // rows rs + 64*i
        f4add(acc, x4[base + (size_t)i * 64 * (D_ / 4)]);
    s_acc[t] = acc;
    __syncthreads();
    for (int off = 128; off >= 4; off >>= 1) {
        if (t < off) f4add(s_acc[t], s_acc[t + off]);
        __syncthreads();
    }
    // s_acc[0..3] = cs[16] = colsum of the 16-float slice of x[b]
    const float* cs = reinterpret_cast<const float*>(s_acc);
    const float4* wv4 = reinterpret_cast<const float4*>(w_qkv);
    float4 vp = make_float4(0.f, 0.f, 0.f, 0.f);
    size_t wbase = (size_t)(s * 16) * (H3_ / 4) + (2 * H_ / 4) + t;
#pragma unroll
    for (int j = 0; j < 16; ++j) {         // 16 contiguous Wv rows, 1KB each
        const float c = cs[j];
        const float4 w = wv4[wbase + (size_t)j * (H3_ / 4)];
        vp.x += c * w.x; vp.y += c * w.y; vp.z += c * w.z; vp.w += c * w.w;
    }
    vspart4[(size_t)(s * 4 + b) * 256 + t] = vp;   // plain store
}

// ---- kOut2: 256 blocks (b, sl in 0..31, rh in 0..1) ------------------------
// fold vspart -> vsum[b] (in LDS), orow 32-col slice = vsum[b]@Wo[:,slice],
// broadcast to 1024 rows as 128B chunks. IDEMPOTENT (launched 5x).
__global__ __launch_bounds__(256) void kOut2(const float4* __restrict__ vspart4,
                                             const float* __restrict__ w_o,
                                             float* __restrict__ out) {
    const int blk = blockIdx.x;
    const int b  = blk >> 6;
    const int sl = (blk >> 1) & 31;
    const int rh = blk & 1;
    const int t  = threadIdx.x;
    __shared__ float4 s_vs4[256];          // vsum[b,:] as 256 float4
    __shared__ float4 s_par[32][8];        // [hg][c] partials, 4KB
    __shared__ float4 s_or4[8];            // 32-col orow slice

    {
        const float4* p = vspart4 + b * 256 + t;
        float4 acc = make_float4(0.f, 0.f, 0.f, 0.f);
#pragma unroll 16
        for (int s = 0; s < 64; ++s)
            f4add(acc, p[(size_t)s * 1024]);
        s_vs4[t] = acc;
    }
    __syncthreads();
    {
        const int c = t & 7, hg = t >> 3;
        const float* vs = reinterpret_cast<const float*>(s_vs4);
        const float4* wo4 = reinterpret_cast<const float4*>(w_o);
        float4 acc = make_float4(0.f, 0.f, 0.f, 0.f);
        size_t wbase = (size_t)(hg * 32) * (D_ / 4) + sl * 8 + c;
#pragma unroll 8
        for (int j = 0; j < 32; ++j) {
            const float v = vs[hg * 32 + j];
            const float4 w = wo4[wbase + (size_t)j * (D_ / 4)];
            acc.x += v * w.x; acc.y += v * w.y; acc.z += v * w.z; acc.w += v * w.w;
        }
        s_par[hg][c] = acc;
    }
    __syncthreads();
    if (t < 8) {
        float4 a = s_par[0][t];
#pragma unroll
        for (int g = 1; g < 32; ++g) f4add(a, s_par[g][t]);
        s_or4[t] = a;
    }
    __syncthreads();
    const float4 val = s_or4[t & 7];
    float4* out4 = reinterpret_cast<float4*>(out);
    const int r0 = rh * 1024 + (t >> 3);   // 32 row streams
    size_t base = ((size_t)b * N_ + r0) * (D_ / 4) + sl * 8 + (t & 7);
#pragma unroll 16
    for (int i = 0; i < 32; ++i)           // rows r0 + 32*i
        out4[base + (size_t)i * 32 * (D_ / 4)] = val;
}

extern "C" void kernel_launch(void* const* d_in, const int* in_sizes, int n_in,
                              void* d_out, int out_size, void* d_ws, size_t ws_size,
                              hipStream_t stream) {
    const float* x     = (const float*)d_in[0];   // [B, N, D]
    const float* w_qkv = (const float*)d_in[1];   // [D, 3H]
    const float* w_o   = (const float*)d_in[2];   // [H, D]
    // d_in[3] = alpha — provably unused (a == 1 regardless of alpha).
    float* out = (float*)d_out;                   // [B, N, D] fp32

    float* vspart = (float*)d_ws;                 // 64*4*1024 = 262144 floats

    kXV<<<256, 256, 0, stream>>>(x, w_qkv, (float4*)vspart);
    // kOut2 is idempotent: 5 replays for slope calibration.
    kOut2<<<256, 256, 0, stream>>>((const float4*)vspart, w_o, out);
    kOut2<<<256, 256, 0, stream>>>((const float4*)vspart, w_o, out);
    kOut2<<<256, 256, 0, stream>>>((const float4*)vspart, w_o, out);
    kOut2<<<256, 256, 0, stream>>>((const float4*)vspart, w_o, out);
    kOut2<<<256, 256, 0, stream>>>((const float4*)vspart, w_o, out);
}

// Round 15
// 30.318 us; speedup vs baseline: 2.6028x; 2.6028x over previous
//
#include <hip/hip_runtime.h>

// PolyAttn collapse: a = s^4/|s^4| == 1.0 identically, so
//   out[b,n,:] = vsum[b,:] @ w_o  (independent of n, q, k, alpha),
//   vsum[b,:]  = (sum_n x[b,n,:]) @ w_qkv[:, 2H:3H].
// R15: calibration (R14) found the law: strided access at 64/128-B chunk
// granularity runs at 1.9-2.7 TB/s; >=256-B chunks run ~6 TB/s. All prior
// ~30us pipelines had a 64/128-B-granular stage. This one has none:
//   kXV2: colsum x in 256-B chunks (R7-kA's proven pattern) + 4KB-row Wv.
//   kOB2: 4KB-contiguous fold + 256-B Wo + 256-B out writes.
// 2 nodes, no atomics, no zero-init. Grid barriers / spin-waits banned.

#define B_ 4
#define N_ 2048
#define D_ 1024
#define H_ 1024
#define H3_ 3072

__device__ __forceinline__ void f4add(float4& a, const float4 b) {
    a.x += b.x; a.y += b.y; a.z += b.z; a.w += b.w;
}

// ws layout (floats): vspart[64][4][1024] (1 MB); p = s*4 + rq

// ---- kXV2: 256 blocks (b, s in 0..15, rq in 0..3) --------------------------
// colsum x[b, rq*512..+512, s*64..+64] (256-B chunks), then through
// Wv rows s*64..+64 (4KB contiguous each) -> vspart[p][b][1024].
__global__ __launch_bounds__(256) void kXV2(const float* __restrict__ x,
                                            const float* __restrict__ w_qkv,
                                            float4* __restrict__ vspart4) {
    const int blk = blockIdx.x;
    const int b  = blk >> 6;
    const int s  = (blk >> 2) & 15;
    const int rq = blk & 3;
    const int t  = threadIdx.x;
    const int c  = t & 15;                 // float4 col within 64-float slice
    const int rs = t >> 4;                 // 16 row streams
    __shared__ float4 s_acc[256];

    // colsum: 512 rows, each stream takes 32 rows at stride 16
    const float4* x4 = reinterpret_cast<const float4*>(x);
    float4 acc = make_float4(0.f, 0.f, 0.f, 0.f);
    size_t base = ((size_t)b * N_ + rq * 512 + rs) * (D_ / 4) + s * 16 + c;
#pragma unroll 16
    for (int i = 0; i < 32; ++i)
        f4add(acc, x4[base + (size_t)i * 16 * (D_ / 4)]);
    s_acc[t] = acc;
    __syncthreads();
    for (int off = 128; off >= 16; off >>= 1) {   // reduce 16 row streams
        if (t < off) f4add(s_acc[t], s_acc[t + off]);
        __syncthreads();
    }
    // s_acc[0..15] = cs[64] = partial colsum of d-slice s*64..+64
    const float* cs = reinterpret_cast<const float*>(s_acc);
    const float4* wv4 = reinterpret_cast<const float4*>(w_qkv);
    // vp[h-f4 owned by t]: 256 threads x f4 = 1024 h
    float4 vp = make_float4(0.f, 0.f, 0.f, 0.f);
    size_t wbase = (size_t)(s * 64) * (H3_ / 4) + (2 * H_ / 4) + t;
#pragma unroll 8
    for (int j = 0; j < 64; ++j) {         // 64 contiguous Wv rows, 4KB each
        const float cj = cs[j];            // LDS broadcast
        const float4 w = wv4[wbase + (size_t)j * (H3_ / 4)];
        vp.x += cj * w.x; vp.y += cj * w.y; vp.z += cj * w.z; vp.w += cj * w.w;
    }
    vspart4[(size_t)((s * 4 + rq) * 4 + b) * 256 + t] = vp;
}

// ---- kOB2: 256 blocks (b, sl in 0..15, rq in 0..3) -------------------------
// fold vspart -> vsum[b] (4KB-contiguous reads), orow slice sl*64..+64 via
// Wo 256-B chunks, write rows rq*512..+512 in 256-B chunks.
__global__ __launch_bounds__(256) void kOB2(const float4* __restrict__ vspart4,
                                            const float* __restrict__ w_o,
                                            float* __restrict__ out) {
    const int blk = blockIdx.x;
    const int b  = blk >> 6;
    const int sl = (blk >> 2) & 15;
    const int rq = blk & 3;
    const int t  = threadIdx.x;
    __shared__ float4 s_vs4[256];          // vsum[b,:]
    __shared__ float4 s_par[256];          // [hg*16+c] partials

    // fold 64 partials (each read: 256 thr x 16B = 4KB contiguous)
    {
        const float4* p = vspart4 + b * 256 + t;
        float4 acc = make_float4(0.f, 0.f, 0.f, 0.f);
#pragma unroll 16
        for (int pp = 0; pp < 64; ++pp)
            f4add(acc, p[(size_t)pp * 1024]);
        s_vs4[t] = acc;
    }
    __syncthreads();
    // orow slice: hg = t>>4 (16 groups x 64 h), c = t&15 (16 f4 cols)
    {
        const int c = t & 15, hg = t >> 4;
        const float* vs = reinterpret_cast<const float*>(s_vs4);
        const float4* wo4 = reinterpret_cast<const float4*>(w_o);
        float4 acc = make_float4(0.f, 0.f, 0.f, 0.f);
        size_t wbase = (size_t)(hg * 64) * (D_ / 4) + sl * 16 + c;
#pragma unroll 8
        for (int j = 0; j < 64; ++j) {     // 256-B chunk per 16-lane group
            const float v = vs[hg * 64 + j];
            const float4 w = wo4[wbase + (size_t)j * (D_ / 4)];
            acc.x += v * w.x; acc.y += v * w.y; acc.z += v * w.z; acc.w += v * w.w;
        }
        s_par[t] = acc;
    }
    __syncthreads();
    for (int off = 128; off >= 16; off >>= 1) {   // fold 16 h-groups
        if (t < off) f4add(s_par[t], s_par[t + off]);
        __syncthreads();
    }
    // s_par[0..15] = orow slice (64 floats); broadcast to 512 rows
    const float4 val = s_par[t & 15];
    float4* out4 = reinterpret_cast<float4*>(out);
    const int rs = t >> 4;                 // 16 row streams x 32 rows
    size_t base = ((size_t)b * N_ + rq * 512 + rs) * (D_ / 4) + sl * 16 + (t & 15);
#pragma unroll 16
    for (int i = 0; i < 32; ++i)
        out4[base + (size_t)i * 16 * (D_ / 4)] = val;
}

extern "C" void kernel_launch(void* const* d_in, const int* in_sizes, int n_in,
                              void* d_out, int out_size, void* d_ws, size_t ws_size,
                              hipStream_t stream) {
    const float* x     = (const float*)d_in[0];   // [B, N, D]
    const float* w_qkv = (const float*)d_in[1];   // [D, 3H]
    const float* w_o   = (const float*)d_in[2];   // [H, D]
    // d_in[3] = alpha — provably unused (a == 1 regardless of alpha).
    float* out = (float*)d_out;                   // [B, N, D] fp32

    float* vspart = (float*)d_ws;                 // 64*4*1024 = 262144 floats

    kXV2<<<256, 256, 0, stream>>>(x, w_qkv, (float4*)vspart);
    kOB2<<<256, 256, 0, stream>>>((const float4*)vspart, w_o, out);
}